// Round 10
// baseline (204.826 us; speedup 1.0000x reference)
//
#include <hip/hip_runtime.h>
#include <stdint.h>

// Y = tanh(X @ W + b):  M=65536 (8*64*128), K=512, N=512, all fp32.
// R10: NO LDS, NO BARRIERS. Key fact: the mfma_32x32x16_bf16 A-fragment is
// 8 contiguous k of one row (row=lane&31, k=hi1*8+[0..7]) = 32 contiguous
// bytes of X; the B-fragment is 16 contiguous bytes of W^T (bf16). So load
// fragments DIRECTLY global->register: per k16-step 4 A dwordx4 + 2 B
// dwordx4 + 8 cvt_pk + 4 MFMA. Each wave is a fully independent pipeline
// (per-wave vmcnt only); 16 waves/CU desync and hide L2 latency (X strips
// are L2-hot: 4 bn-blocks/strip on the same XCD via swizzle; FETCH=70MB).
// A-rows are wave-exclusive so LDS staging bought nothing for A; B-tile
// reuse is in-register via the 32x32 MFMA structure.
// Depth-1 prefetch: VM(0) -> cvt A(t) (frees fp32 regs) -> issue t+1 ->
// MFMA(t). Reg budget ~56 VGPR + 64 AGPR < 128 -> 4 waves/SIMD.
// R9 lesson: barrier-convoyed LDS structure capped at MfmaUtil 14%.

typedef short bf16x8 __attribute__((ext_vector_type(8)));
typedef float f32x16 __attribute__((ext_vector_type(16)));
typedef uint32_t u32x4 __attribute__((ext_vector_type(4)));

#define KTOT 512
#define NTOT 512
#define WT_BYTES   524288ull      // 512*512*2
#define WS_NEEDED  WT_BYTES

__device__ __forceinline__ uint32_t pk2(float a, float b) {
  uint16_t lo = __builtin_bit_cast(uint16_t, (__bf16)a);   // RNE
  uint16_t hi = __builtin_bit_cast(uint16_t, (__bf16)b);
  return (uint32_t)lo | ((uint32_t)hi << 16);
}

__device__ __forceinline__ bf16x8 pack8(float4 a, float4 b) {
  u32x4 t;
  t.x = pk2(a.x, a.y); t.y = pk2(a.z, a.w);
  t.z = pk2(b.x, b.y); t.w = pk2(b.z, b.w);
  return __builtin_bit_cast(bf16x8, t);
}

__device__ __forceinline__ float fast_tanh(float z) {
  float t = __builtin_amdgcn_exp2f(z * 2.8853900817779268f);
  return 1.0f - 2.0f * __builtin_amdgcn_rcpf(t + 1.0f);
}

// ---- pass 1: W fp32 [k][n] -> plain bf16 transpose Wt [n:512][k:512] ----
__global__ __launch_bounds__(256)
void cvtW_kernel(const float* __restrict__ W, uint8_t* __restrict__ Wt) {
  const int c  = blockIdx.x * 256 + threadIdx.x;   // 0..32767
  const int n  = c >> 6;                           // 0..511
  const int k0 = (c & 63) * 8;
  float e[8];
#pragma unroll
  for (int i = 0; i < 8; ++i) e[i] = W[(size_t)(k0 + i) * NTOT + n];
  uint4 v = make_uint4(pk2(e[0], e[1]), pk2(e[2], e[3]),
                       pk2(e[4], e[5]), pk2(e[6], e[7]));
  *(uint4*)(Wt + (size_t)n * (KTOT * 2) + k0 * 2) = v;
}

// ---------------- pass 2: register-direct GEMM + bias + tanh ----------------
__global__ __launch_bounds__(256, 4)
void hotdd_fused(const float* __restrict__ X, const uint8_t* __restrict__ Wt,
                 const float* __restrict__ Bv, float* __restrict__ Y) {
  // XCD swizzle: the 4 bn-blocks sharing an X strip -> same XCD, adjacent.
  const int d  = blockIdx.x;
  const int bm = ((d >> 5) << 3) | (d & 7);   // 0..511
  const int bn = (d >> 3) & 3;                // 0..3

  const int tid  = threadIdx.x;
  const int lane = tid & 63;
  const int wv   = tid >> 6;
  const int wr   = (wv >> 1) * 64;   // wave M offset in 128-tile
  const int wc   = (wv & 1) * 64;    // wave N offset
  const int lo5  = lane & 31;
  const int hi1  = lane >> 5;

  // fragment source pointers (fixed per lane; step advances via immediates)
  const float*   pA0 = X  + (size_t)(bm * 128 + wr + lo5) * KTOT + hi1 * 8;
  const float*   pA1 = pA0 + (size_t)32 * KTOT;
  const uint8_t* pB0 = Wt + (size_t)(bn * 128 + wc + lo5) * (KTOT * 2) + hi1 * 16;
  const uint8_t* pB1 = pB0 + (size_t)32 * (KTOT * 2);

  float4 af00, af01, af10, af11;    // A(t) fp32 (freed by cvt each step)
  bf16x8 fbE0, fbE1, fbO0, fbO1;    // B parity sets (loaded direct as bf16)
  f32x16 acc00 = {}, acc01 = {}, acc10 = {}, acc11 = {};

#define SEP()  asm volatile("" ::: "memory")
#define VM0()  asm volatile("s_waitcnt vmcnt(0)" ::: "memory")

#define LOADA(T) do {                                                         \
    af00 = *(const float4*)(pA0 + (T) * 16);                                  \
    af01 = *(const float4*)(pA0 + (T) * 16 + 4);                              \
    af10 = *(const float4*)(pA1 + (T) * 16);                                  \
    af11 = *(const float4*)(pA1 + (T) * 16 + 4);                              \
  } while (0)

#define LOADB(B0, B1, T) do {                                                 \
    B0 = *(const bf16x8*)(pB0 + (T) * 32);                                    \
    B1 = *(const bf16x8*)(pB1 + (T) * 32);                                    \
  } while (0)

#define STEP(T, BC0, BC1, BN0, BN1) do {                                      \
    VM0();                          /* A(T), B(T) landed */                   \
    bf16x8 fa0 = pack8(af00, af01);                                           \
    bf16x8 fa1 = pack8(af10, af11);                                           \
    SEP();                                                                    \
    if ((T) + 1 < 32) {             /* issue next; flies over MFMA */         \
      LOADA((T) + 1);                                                         \
      LOADB(BN0, BN1, (T) + 1);                                               \
      SEP();                                                                  \
    }                                                                         \
    acc00 = __builtin_amdgcn_mfma_f32_32x32x16_bf16(fa0, BC0, acc00, 0,0,0);  \
    acc01 = __builtin_amdgcn_mfma_f32_32x32x16_bf16(fa0, BC1, acc01, 0,0,0);  \
    acc10 = __builtin_amdgcn_mfma_f32_32x32x16_bf16(fa1, BC0, acc10, 0,0,0);  \
    acc11 = __builtin_amdgcn_mfma_f32_32x32x16_bf16(fa1, BC1, acc11, 0,0,0);  \
  } while (0)

  // prologue: A(0), B(0) in flight
  LOADA(0);
  LOADB(fbE0, fbE1, 0);
  SEP();

#pragma unroll
  for (int u = 0; u < 16; ++u) {
    STEP(2 * u,     fbE0, fbE1, fbO0, fbO1);
    STEP(2 * u + 1, fbO0, fbO1, fbE0, fbE1);
  }

  // ---- epilogue: bias + tanh + fp32 store
  const int gn0 = bn * 128 + wc + lo5;
  const int gn1 = gn0 + 32;
  const float bv0 = Bv[gn0];
  const float bv1 = Bv[gn1];

#define EPI(ACC, MI, GN, BVAL) do {                                           \
    _Pragma("unroll")                                                         \
    for (int r = 0; r < 16; ++r) {                                            \
      const int mloc = wr + (MI) * 32 + (hi1 << 2) + ((r >> 2) << 3) + (r & 3);\
      Y[(size_t)(bm * 128 + mloc) * NTOT + (GN)] = fast_tanh((ACC)[r] + (BVAL));\
    }                                                                         \
  } while (0)

  EPI(acc00, 0, gn0, bv0);
  EPI(acc01, 0, gn1, bv1);
  EPI(acc10, 1, gn0, bv0);
  EPI(acc11, 1, gn1, bv1);
}

// ---------------- fallback: R1 kernel (146us), used if ws too small ----------
struct Regs {
  float4 a0,a1,a2,a3,a4,a5,a6,a7;
  float4 u0,u1,u2,u3;
  float4 v0,v1,v2,v3;
};

__device__ __forceinline__ uint32_t pk2f(float a, float b) { return pk2(a, b); }

__global__ __launch_bounds__(256, 2)
void hotdd_fallback(const float* __restrict__ X, const float* __restrict__ W,
                    const float* __restrict__ Bv, float* __restrict__ Y) {
  __shared__ char Ab[128 * 64 * 2];
  __shared__ char Bb[128 * 64 * 2];
  const int d  = blockIdx.x;
  const int bm = ((d >> 5) << 3) | (d & 7);
  const int bn = (d >> 3) & 3;
  const int tid  = threadIdx.x;
  const int lane = tid & 63;
  const int wv   = tid >> 6;
  const int wr   = (wv >> 1) * 64;
  const int wc   = (wv & 1) * 64;
  const int lo5  = lane & 31;
  const int hi1  = lane >> 5;
  const int rs   = lo5 & 7;
  const int am   = tid >> 1;
  const int ah   = tid & 1;
  const int amz  = am & 7;
  const int abase = am * 128;
  const float* Ag = X + (size_t)(bm * 128 + am) * KTOT + ah * 32;
  const int kp = lo5;
  const int ng = wv * 32 + hi1 * 16;
  const float* Bg = W + (size_t)(2 * kp) * NTOT + bn * 128 + ng;

#define LOADR(R, K0) do {                                                     \
    const float* ap_ = Ag + (K0);                                             \
    R.a0 = *(const float4*)(ap_ +  0); R.a1 = *(const float4*)(ap_ +  4);     \
    R.a2 = *(const float4*)(ap_ +  8); R.a3 = *(const float4*)(ap_ + 12);     \
    R.a4 = *(const float4*)(ap_ + 16); R.a5 = *(const float4*)(ap_ + 20);     \
    R.a6 = *(const float4*)(ap_ + 24); R.a7 = *(const float4*)(ap_ + 28);     \
    const float* bp_ = Bg + (size_t)(K0) * NTOT;                              \
    R.u0 = *(const float4*)(bp_ +  0); R.u1 = *(const float4*)(bp_ +  4);     \
    R.u2 = *(const float4*)(bp_ +  8); R.u3 = *(const float4*)(bp_ + 12);     \
    R.v0 = *(const float4*)(bp_ + NTOT +  0); R.v1 = *(const float4*)(bp_ + NTOT +  4); \
    R.v2 = *(const float4*)(bp_ + NTOT +  8); R.v3 = *(const float4*)(bp_ + NTOT + 12); \
  } while (0)

#define ASTF(R, J, P, Q)                                                      \
    *(uint4*)(Ab + abase + (((((ah << 2) + (J)) ^ amz)) << 4)) =              \
      make_uint4(pk2f(R.P.x, R.P.y), pk2f(R.P.z, R.P.w),                      \
                 pk2f(R.Q.x, R.Q.y), pk2f(R.Q.z, R.Q.w));
#define BSTF(R, I, UV, C)                                                     \
    *(uint32_t*)(Bb + (ng + (I)) * 128 + ((kp << 2) ^ (((I) & 7) << 4))) =    \
      pk2f(R.u##UV.C, R.v##UV.C);

#define STORERF(R) do {                                                       \
    ASTF(R, 0, a0, a1) ASTF(R, 1, a2, a3) ASTF(R, 2, a4, a5) ASTF(R, 3, a6, a7)\
    BSTF(R, 0, 0, x) BSTF(R, 1, 0, y) BSTF(R, 2, 0, z) BSTF(R, 3, 0, w)       \
    BSTF(R, 4, 1, x) BSTF(R, 5, 1, y) BSTF(R, 6, 1, z) BSTF(R, 7, 1, w)       \
    BSTF(R, 8, 2, x) BSTF(R, 9, 2, y) BSTF(R,10, 2, z) BSTF(R,11, 2, w)       \
    BSTF(R,12, 3, x) BSTF(R,13, 3, y) BSTF(R,14, 3, z) BSTF(R,15, 3, w)       \
  } while (0)

  f32x16 acc00 = {}, acc01 = {}, acc10 = {}, acc11 = {};
  const char* Ard0 = Ab + (wr + lo5) * 128;
  const char* Ard1 = Ard0 + 32 * 128;
  const char* Brd0 = Bb + (wc + lo5) * 128;
  const char* Brd1 = Brd0 + 32 * 128;

#define MFMA_PHASE_F() do {                                                   \
    _Pragma("unroll")                                                         \
    for (int kk = 0; kk < 4; ++kk) {                                          \
      const int sb = ((((kk << 1) | hi1) ^ rs) << 4);                         \
      bf16x8 fa0 = *(const bf16x8*)(Ard0 + sb);                               \
      bf16x8 fa1 = *(const bf16x8*)(Ard1 + sb);                               \
      bf16x8 fb0 = *(const bf16x8*)(Brd0 + sb);                               \
      bf16x8 fb1 = *(const bf16x8*)(Brd1 + sb);                               \
      acc00 = __builtin_amdgcn_mfma_f32_32x32x16_bf16(fa0, fb0, acc00, 0,0,0);\
      acc01 = __builtin_amdgcn_mfma_f32_32x32x16_bf16(fa0, fb1, acc01, 0,0,0);\
      acc10 = __builtin_amdgcn_mfma_f32_32x32x16_bf16(fa1, fb0, acc10, 0,0,0);\
      acc11 = __builtin_amdgcn_mfma_f32_32x32x16_bf16(fa1, fb1, acc11, 0,0,0);\
    }                                                                         \
  } while (0)

  Regs r0, r1;
  LOADR(r0, 0);
#pragma unroll 1
  for (int s = 0; s < 8; s += 2) {
    STORERF(r0);
    __syncthreads();
    LOADR(r1, (s + 1) * 64);
    MFMA_PHASE_F();
    __syncthreads();
    STORERF(r1);
    __syncthreads();
    if (s + 2 < 8) LOADR(r0, (s + 2) * 64);
    MFMA_PHASE_F();
    __syncthreads();
  }

  const int gn0 = bn * 128 + wc + lo5;
  const int gn1 = gn0 + 32;
  const float bv0 = Bv[gn0];
  const float bv1 = Bv[gn1];
  EPI(acc00, 0, gn0, bv0);
  EPI(acc01, 0, gn1, bv1);
  EPI(acc10, 1, gn0, bv0);
  EPI(acc11, 1, gn1, bv1);
}

extern "C" void kernel_launch(void* const* d_in, const int* in_sizes, int n_in,
                              void* d_out, int out_size, void* d_ws, size_t ws_size,
                              hipStream_t stream) {
  (void)in_sizes; (void)n_in; (void)out_size;
  const float* X = (const float*)d_in[0];
  const float* W = (const float*)d_in[1];
  const float* b = (const float*)d_in[2];
  float* Y = (float*)d_out;
  if (ws_size >= WS_NEEDED) {
    uint8_t* Wt = (uint8_t*)d_ws;
    hipLaunchKernelGGL(cvtW_kernel, dim3(128),  dim3(256), 0, stream, W, Wt);
    hipLaunchKernelGGL(hotdd_fused, dim3(2048), dim3(256), 0, stream, X, Wt, b, Y);
  } else {
    hipLaunchKernelGGL(hotdd_fallback, dim3(2048), dim3(256), 0, stream, X, W, b, Y);
  }
}

// Round 11
// 81.246 us; speedup vs baseline: 2.5211x; 2.5211x over previous
//
#include <hip/hip_runtime.h>
#include <stdint.h>

// Y = tanh(X @ W + b):  M=65536 (8*64*128), K=512, N=512, all fp32.
// R11: R9 + 3-deep LDS buffer rotation (BK=32, 16 K-steps). Every dependency
// now has ~2 steps of slack:
//   - BGLDS(t+2) issued at step t, consumed at t+2 (~1400cy cover)
//   - LOADA(t+2) issued at step t, CVTA'd at t+1, consumed at t+2
//   - buffer written at step t was last READ at t-3 -> the 1/step barrier
//     arrives pre-satisfied (R9 had zero recycle slack -> convoy)
// One VM(6)/step retires A(t+1)+B(t+1) together. Never vmcnt(0) in loop.
// LDS 6x8KB = 48KB -> 3 blocks/CU; ~70 VGPR + 64 AGPR under (256,3) cap 170.
// R10 lesson: fragment loads from global are inherently uncoalesced (rows
// 2KB apart); LDS staging IS the coalescing device.

typedef short bf16x8 __attribute__((ext_vector_type(8)));
typedef float f32x16 __attribute__((ext_vector_type(16)));

#define KTOT 512
#define NTOT 512
#define WT_BYTES   524288ull      // 512*512*2
#define WS_NEEDED  WT_BYTES

typedef __attribute__((address_space(3))) uint8_t lds8;
typedef __attribute__((address_space(1))) const uint8_t glb8;

__device__ __forceinline__ uint32_t pk2(float a, float b) {
  uint16_t lo = __builtin_bit_cast(uint16_t, (__bf16)a);   // RNE
  uint16_t hi = __builtin_bit_cast(uint16_t, (__bf16)b);
  return (uint32_t)lo | ((uint32_t)hi << 16);
}

__device__ __forceinline__ float fast_tanh(float z) {
  float t = __builtin_amdgcn_exp2f(z * 2.8853900817779268f);
  return 1.0f - 2.0f * __builtin_amdgcn_rcpf(t + 1.0f);
}

__device__ __forceinline__ int swz4(int r) { return ((r >> 1) ^ (r >> 3)) & 3; }

// ---- pass 1: W fp32 [k][n] -> bf16 transposed swizzled image, BK=32 tiles --
// 64 tiles (bn*16+s) of 8KB: [r:128 rows][4 slots x 16B]; chunk j of row r
// (k = s*32 + j*8 ..+7, col n = bn*128+r) stored at slot j ^ swz4(r).
__global__ __launch_bounds__(256)
void cvtW_kernel(const float* __restrict__ W, uint8_t* __restrict__ Wt) {
  const int c    = blockIdx.x * 256 + threadIdx.x;   // 0..32767
  const int j    = c & 3;
  const int r    = (c >> 2) & 127;
  const int tile = c >> 9;                           // bn*16 + s, 0..63
  const int s    = tile & 15;
  const int bn   = tile >> 4;
  const int n    = bn * 128 + r;
  const int k0   = s * 32 + j * 8;
  float e[8];
#pragma unroll
  for (int i = 0; i < 8; ++i) e[i] = W[(size_t)(k0 + i) * NTOT + n];
  uint4 v = make_uint4(pk2(e[0], e[1]), pk2(e[2], e[3]),
                       pk2(e[4], e[5]), pk2(e[6], e[7]));
  *(uint4*)(Wt + ((size_t)tile << 13) + (r << 6) + ((j ^ swz4(r)) << 4)) = v;
}

// ---------------- pass 2: fused GEMM + bias + tanh ----------------
__global__ __launch_bounds__(256, 3)
void hotdd_fused(const float* __restrict__ X, const uint8_t* __restrict__ Wt,
                 const float* __restrict__ Bv, float* __restrict__ Y) {
  __shared__ uint8_t Ab0[8192], Ab1[8192], Ab2[8192];
  __shared__ uint8_t Bb0[8192], Bb1[8192], Bb2[8192];

  // XCD swizzle: the 4 bn-blocks sharing an X strip -> same XCD, adjacent.
  const int d  = blockIdx.x;
  const int bm = ((d >> 5) << 3) | (d & 7);   // 0..511
  const int bn = (d >> 3) & 3;                // 0..3

  const int tid  = threadIdx.x;
  const int lane = tid & 63;
  const int wv   = tid >> 6;
  const int wr   = (wv >> 1) * 64;
  const int wc   = (wv & 1) * 64;
  const int lo5  = lane & 31;
  const int hi1  = lane >> 5;

  // ---- A staging map: lane -> row arow = wv*32 + (lane>>1), k-half ahalf.
  const int arow  = wv * 32 + (lane >> 1);
  const int ahalf = lane & 1;
  const float* pA = X + (size_t)(bm * 128 + arow) * KTOT + ahalf * 16;
  const int ak  = swz4(arow);
  const int aw0 = arow * 64 + ((((ahalf << 1) | 0) ^ ak) << 4);
  const int aw1 = arow * 64 + ((((ahalf << 1) | 1) ^ ak) << 4);

  // ---- B staging: wave wv copies bytes [wv*2048, +2048) of the 8KB tile.
  const uint8_t* pB = Wt + ((size_t)(bn * 16) << 13) + wv * 2048 + lane * 16;

  // ---- fragment read offsets (64B rows, swizzled slots)
  const int rA0 = wr + lo5, rA1 = rA0 + 32;
  const int rB0 = wc + lo5, rB1 = rB0 + 32;
  const int oA0 = rA0 * 64, oA1 = rA1 * 64;
  const int oB0 = rB0 * 64, oB1 = rB1 * 64;
  const int kA0 = swz4(rA0), kA1 = swz4(rA1);
  const int kB0 = swz4(rB0), kB1 = swz4(rB1);

  float4 ra0, ra1, ra2, ra3;        // A-prefetch reg set a
  float4 rb0, rb1, rb2, rb3;        // A-prefetch reg set b
  f32x16 acc00 = {}, acc01 = {}, acc10 = {}, acc11 = {};

#define SEP() asm volatile("" ::: "memory")
#define VM(N)  asm volatile("s_waitcnt vmcnt(" #N ")" ::: "memory")
#define LGKM0() asm volatile("s_waitcnt lgkmcnt(0)" ::: "memory")

#define BGLDS(BD, S) do {                                                     \
    const uint8_t* bs_ = pB + ((size_t)(S) << 13);                            \
    __builtin_amdgcn_global_load_lds((glb8*)bs_,                              \
                                     (lds8*)((BD) + wv * 2048), 16, 0, 0);    \
    __builtin_amdgcn_global_load_lds((glb8*)(bs_ + 1024),                     \
                                     (lds8*)((BD) + wv * 2048 + 1024),        \
                                     16, 0, 0);                               \
    SEP();                                                                    \
  } while (0)

#define LOADA(R0, R1, R2, R3, S) do {                                         \
    const float* ap_ = pA + (S) * 32;                                         \
    R0 = *(const float4*)(ap_ + 0);  R1 = *(const float4*)(ap_ + 4);          \
    R2 = *(const float4*)(ap_ + 8);  R3 = *(const float4*)(ap_ + 12);         \
    SEP();                                                                    \
  } while (0)

#define CVTA(R0, R1, R2, R3, AB) do {                                         \
    *(uint4*)((AB) + aw0) = make_uint4(pk2(R0.x, R0.y), pk2(R0.z, R0.w),      \
                                       pk2(R1.x, R1.y), pk2(R1.z, R1.w));     \
    *(uint4*)((AB) + aw1) = make_uint4(pk2(R2.x, R2.y), pk2(R2.z, R2.w),      \
                                       pk2(R3.x, R3.y), pk2(R3.z, R3.w));     \
  } while (0)

#define MFMA_STEP(AB, BB) do {                                                \
    _Pragma("unroll")                                                         \
    for (int kk = 0; kk < 2; ++kk) {                                          \
      const int c_ = (kk << 1) | hi1;                                         \
      bf16x8 fa0 = *(const bf16x8*)((AB) + oA0 + ((c_ ^ kA0) << 4));          \
      bf16x8 fa1 = *(const bf16x8*)((AB) + oA1 + ((c_ ^ kA1) << 4));          \
      bf16x8 fb0 = *(const bf16x8*)((BB) + oB0 + ((c_ ^ kB0) << 4));          \
      bf16x8 fb1 = *(const bf16x8*)((BB) + oB1 + ((c_ ^ kB1) << 4));          \
      acc00 = __builtin_amdgcn_mfma_f32_32x32x16_bf16(fa0, fb0, acc00, 0,0,0);\
      acc01 = __builtin_amdgcn_mfma_f32_32x32x16_bf16(fa0, fb1, acc01, 0,0,0);\
      acc10 = __builtin_amdgcn_mfma_f32_32x32x16_bf16(fa1, fb0, acc10, 0,0,0);\
      acc11 = __builtin_amdgcn_mfma_f32_32x32x16_bf16(fa1, fb1, acc11, 0,0,0);\
    }                                                                         \
  } while (0)

// One K-step. Reads buf[t%3]; CVTA(A(t+1)) -> Abuf[(t+1)%3] (last read t-2);
// BGLDS(t+2) -> Bbuf[(t+2)%3] (last read t-1, covered by barrier at t).
// VM(6) retires A(t+1) AND B(t+1) (queue: [B(t+1):2, A(t+1):4, B(t+2):2,
// A(t+2):4] -> keep 6 newest).
#define STEPX(T, ABC, BBC, ABW, BBW, L0,L1,L2,L3, C0,C1,C2,C3) do {           \
    __builtin_amdgcn_s_barrier();                                             \
    BGLDS(BBW, (T) + 2);                                                      \
    LOADA(L0, L1, L2, L3, (T) + 2);                                           \
    MFMA_STEP(ABC, BBC);                                                      \
    VM(6);                                                                    \
    CVTA(C0, C1, C2, C3, ABW);                                                \
    LGKM0();                                                                  \
  } while (0)

  // ---- prologue: stage steps 0 and 1; CVT A(0) into Abuf0.
  BGLDS(Bb0, 0);
  LOADA(ra0, ra1, ra2, ra3, 0);
  BGLDS(Bb1, 1);
  LOADA(rb0, rb1, rb2, rb3, 1);
  VM(6);                            // retires B(0), A(0)
  CVTA(ra0, ra1, ra2, ra3, Ab0);
  LGKM0();

  // ---- main: steps 0..13 (period-6 buffer/reg pattern), tail 14,15.
#pragma unroll 1
  for (int t = 0; t < 12; t += 6) {
    STEPX(t + 0, Ab0, Bb0, Ab1, Bb2, ra0,ra1,ra2,ra3, rb0,rb1,rb2,rb3);
    STEPX(t + 1, Ab1, Bb1, Ab2, Bb0, rb0,rb1,rb2,rb3, ra0,ra1,ra2,ra3);
    STEPX(t + 2, Ab2, Bb2, Ab0, Bb1, ra0,ra1,ra2,ra3, rb0,rb1,rb2,rb3);
    STEPX(t + 3, Ab0, Bb0, Ab1, Bb2, rb0,rb1,rb2,rb3, ra0,ra1,ra2,ra3);
    STEPX(t + 4, Ab1, Bb1, Ab2, Bb0, ra0,ra1,ra2,ra3, rb0,rb1,rb2,rb3);
    STEPX(t + 5, Ab2, Bb2, Ab0, Bb1, rb0,rb1,rb2,rb3, ra0,ra1,ra2,ra3);
  }
  STEPX(12, Ab0, Bb0, Ab1, Bb2, ra0,ra1,ra2,ra3, rb0,rb1,rb2,rb3); // pre 14
  STEPX(13, Ab1, Bb1, Ab2, Bb0, rb0,rb1,rb2,rb3, ra0,ra1,ra2,ra3); // pre 15

  // t=14: no more prefetch; CVT A(15) -> Abuf0 (last read t=12).
  __builtin_amdgcn_s_barrier();
  MFMA_STEP(Ab2, Bb2);
  VM(0);                            // A(15), B(15) landed
  CVTA(rb0, rb1, rb2, rb3, Ab0);
  LGKM0();
  // t=15:
  __builtin_amdgcn_s_barrier();
  MFMA_STEP(Ab0, Bb0);

  // ---- epilogue: bias + tanh + fp32 store
  const int gn0 = bn * 128 + wc + lo5;
  const int gn1 = gn0 + 32;
  const float bv0 = Bv[gn0];
  const float bv1 = Bv[gn1];

#define EPI(ACC, MI, GN, BVAL) do {                                           \
    _Pragma("unroll")                                                         \
    for (int r = 0; r < 16; ++r) {                                            \
      const int mloc = wr + (MI) * 32 + (hi1 << 2) + ((r >> 2) << 3) + (r & 3);\
      Y[(size_t)(bm * 128 + mloc) * NTOT + (GN)] = fast_tanh((ACC)[r] + (BVAL));\
    }                                                                         \
  } while (0)

  EPI(acc00, 0, gn0, bv0);
  EPI(acc01, 0, gn1, bv1);
  EPI(acc10, 1, gn0, bv0);
  EPI(acc11, 1, gn1, bv1);
}

// ---------------- fallback: R1 kernel (146us), used if ws too small ----------
struct Regs {
  float4 a0,a1,a2,a3,a4,a5,a6,a7;
  float4 u0,u1,u2,u3;
  float4 v0,v1,v2,v3;
};

__global__ __launch_bounds__(256, 2)
void hotdd_fallback(const float* __restrict__ X, const float* __restrict__ W,
                    const float* __restrict__ Bv, float* __restrict__ Y) {
  __shared__ char Ab[128 * 64 * 2];
  __shared__ char Bb[128 * 64 * 2];
  const int d  = blockIdx.x;
  const int bm = ((d >> 5) << 3) | (d & 7);
  const int bn = (d >> 3) & 3;
  const int tid  = threadIdx.x;
  const int lane = tid & 63;
  const int wv   = tid >> 6;
  const int wr   = (wv >> 1) * 64;
  const int wc   = (wv & 1) * 64;
  const int lo5  = lane & 31;
  const int hi1  = lane >> 5;
  const int rs   = lo5 & 7;
  const int am   = tid >> 1;
  const int ah   = tid & 1;
  const int amz  = am & 7;
  const int abase = am * 128;
  const float* Ag = X + (size_t)(bm * 128 + am) * KTOT + ah * 32;
  const int kp = lo5;
  const int ng = wv * 32 + hi1 * 16;
  const float* Bg = W + (size_t)(2 * kp) * NTOT + bn * 128 + ng;

#define LOADR(R, K0) do {                                                     \
    const float* ap_ = Ag + (K0);                                             \
    R.a0 = *(const float4*)(ap_ +  0); R.a1 = *(const float4*)(ap_ +  4);     \
    R.a2 = *(const float4*)(ap_ +  8); R.a3 = *(const float4*)(ap_ + 12);     \
    R.a4 = *(const float4*)(ap_ + 16); R.a5 = *(const float4*)(ap_ + 20);     \
    R.a6 = *(const float4*)(ap_ + 24); R.a7 = *(const float4*)(ap_ + 28);     \
    const float* bp_ = Bg + (size_t)(K0) * NTOT;                              \
    R.u0 = *(const float4*)(bp_ +  0); R.u1 = *(const float4*)(bp_ +  4);     \
    R.u2 = *(const float4*)(bp_ +  8); R.u3 = *(const float4*)(bp_ + 12);     \
    R.v0 = *(const float4*)(bp_ + NTOT +  0); R.v1 = *(const float4*)(bp_ + NTOT +  4); \
    R.v2 = *(const float4*)(bp_ + NTOT +  8); R.v3 = *(const float4*)(bp_ + NTOT + 12); \
  } while (0)

#define ASTF(R, J, P, Q)                                                      \
    *(uint4*)(Ab + abase + (((((ah << 2) + (J)) ^ amz)) << 4)) =              \
      make_uint4(pk2(R.P.x, R.P.y), pk2(R.P.z, R.P.w),                        \
                 pk2(R.Q.x, R.Q.y), pk2(R.Q.z, R.Q.w));
#define BSTF(R, I, UV, C)                                                     \
    *(uint32_t*)(Bb + (ng + (I)) * 128 + ((kp << 2) ^ (((I) & 7) << 4))) =    \
      pk2(R.u##UV.C, R.v##UV.C);

#define STORERF(R) do {                                                       \
    ASTF(R, 0, a0, a1) ASTF(R, 1, a2, a3) ASTF(R, 2, a4, a5) ASTF(R, 3, a6, a7)\
    BSTF(R, 0, 0, x) BSTF(R, 1, 0, y) BSTF(R, 2, 0, z) BSTF(R, 3, 0, w)       \
    BSTF(R, 4, 1, x) BSTF(R, 5, 1, y) BSTF(R, 6, 1, z) BSTF(R, 7, 1, w)       \
    BSTF(R, 8, 2, x) BSTF(R, 9, 2, y) BSTF(R,10, 2, z) BSTF(R,11, 2, w)       \
    BSTF(R,12, 3, x) BSTF(R,13, 3, y) BSTF(R,14, 3, z) BSTF(R,15, 3, w)       \
  } while (0)

  f32x16 acc00 = {}, acc01 = {}, acc10 = {}, acc11 = {};
  const char* Ard0 = Ab + (wr + lo5) * 128;
  const char* Ard1 = Ard0 + 32 * 128;
  const char* Brd0 = Bb + (wc + lo5) * 128;
  const char* Brd1 = Brd0 + 32 * 128;

#define MFMA_PHASE_F() do {                                                   \
    _Pragma("unroll")                                                         \
    for (int kk = 0; kk < 4; ++kk) {                                          \
      const int sb = ((((kk << 1) | hi1) ^ rs) << 4);                         \
      bf16x8 fa0 = *(const bf16x8*)(Ard0 + sb);                               \
      bf16x8 fa1 = *(const bf16x8*)(Ard1 + sb);                               \
      bf16x8 fb0 = *(const bf16x8*)(Brd0 + sb);                               \
      bf16x8 fb1 = *(const bf16x8*)(Brd1 + sb);                               \
      acc00 = __builtin_amdgcn_mfma_f32_32x32x16_bf16(fa0, fb0, acc00, 0,0,0);\
      acc01 = __builtin_amdgcn_mfma_f32_32x32x16_bf16(fa0, fb1, acc01, 0,0,0);\
      acc10 = __builtin_amdgcn_mfma_f32_32x32x16_bf16(fa1, fb0, acc10, 0,0,0);\
      acc11 = __builtin_amdgcn_mfma_f32_32x32x16_bf16(fa1, fb1, acc11, 0,0,0);\
    }                                                                         \
  } while (0)

  Regs r0, r1;
  LOADR(r0, 0);
#pragma unroll 1
  for (int s = 0; s < 8; s += 2) {
    STORERF(r0);
    __syncthreads();
    LOADR(r1, (s + 1) * 64);
    MFMA_PHASE_F();
    __syncthreads();
    STORERF(r1);
    __syncthreads();
    if (s + 2 < 8) LOADR(r0, (s + 2) * 64);
    MFMA_PHASE_F();
    __syncthreads();
  }

  const int gn0 = bn * 128 + wc + lo5;
  const int gn1 = gn0 + 32;
  const float bv0 = Bv[gn0];
  const float bv1 = Bv[gn1];
  EPI(acc00, 0, gn0, bv0);
  EPI(acc01, 0, gn1, bv1);
  EPI(acc10, 1, gn0, bv0);
  EPI(acc11, 1, gn1, bv1);
}

extern "C" void kernel_launch(void* const* d_in, const int* in_sizes, int n_in,
                              void* d_out, int out_size, void* d_ws, size_t ws_size,
                              hipStream_t stream) {
  (void)in_sizes; (void)n_in; (void)out_size;
  const float* X = (const float*)d_in[0];
  const float* W = (const float*)d_in[1];
  const float* b = (const float*)d_in[2];
  float* Y = (float*)d_out;
  if (ws_size >= WS_NEEDED) {
    uint8_t* Wt = (uint8_t*)d_ws;
    hipLaunchKernelGGL(cvtW_kernel, dim3(128),  dim3(256), 0, stream, W, Wt);
    hipLaunchKernelGGL(hotdd_fused, dim3(2048), dim3(256), 0, stream, X, Wt, b, Y);
  } else {
    hipLaunchKernelGGL(hotdd_fallback, dim3(2048), dim3(256), 0, stream, X, W, b, Y);
  }
}